// Round 1
// baseline (2160.230 us; speedup 1.0000x reference)
//
#include <hip/hip_runtime.h>
#include <stdint.h>

// Problem constants
#define N_ROWS 4096
#define K_DIM  2048
#define V_DIM  50257
#define V_PAD  50304              // 393 * 128
#define VB     393                // number of 128-wide v blocks
#define IGNORE_IDX (-100)

typedef __attribute__((ext_vector_type(8))) __bf16 bf16x8;
typedef __attribute__((ext_vector_type(4))) float floatx4;

typedef __attribute__((address_space(3))) unsigned int lds_uint;
typedef __attribute__((address_space(1))) const unsigned int gbl_uint;

__device__ __forceinline__ void async_copy16(const unsigned short* g, unsigned short* s) {
    // 16B per lane: global -> LDS direct (wave-uniform LDS base + lane*16)
    __builtin_amdgcn_global_load_lds((gbl_uint*)g, (lds_uint*)s, 16, 0, 0);
}

__device__ __forceinline__ unsigned short f2bf(float f) {
    union { float f; unsigned int u; } v; v.f = f;
    unsigned int r = v.u + 0x7fffu + ((v.u >> 16) & 1u);   // RNE
    return (unsigned short)(r >> 16);
}

__device__ __forceinline__ unsigned int pack2(float lo, float hi) {
    return (unsigned int)f2bf(lo) | ((unsigned int)f2bf(hi) << 16);
}

// ---------------- x fp32 -> bf16 ----------------
__global__ void convert_x_kernel(const float* __restrict__ x, unsigned short* __restrict__ xb) {
    size_t i = ((size_t)blockIdx.x * 256 + threadIdx.x) * 8;
    const float4 a = *(const float4*)(x + i);
    const float4 b = *(const float4*)(x + i + 4);
    uint4 o;
    o.x = pack2(a.x, a.y); o.y = pack2(a.z, a.w);
    o.z = pack2(b.x, b.y); o.w = pack2(b.z, b.w);
    *(uint4*)(xb + i) = o;
}

// ---------------- W [K,V] fp32 -> Wt [V_PAD, K] bf16 (transpose+convert) ----------------
__global__ void transpose_w_kernel(const float* __restrict__ W, unsigned short* __restrict__ wt) {
    __shared__ unsigned short tile[64][66];   // [k][v], pad to 66 to spread banks
    const int t  = threadIdx.x;
    const int v0 = blockIdx.x * 64;
    const int k0 = blockIdx.y * 64;
    // phase 1: coalesced read along v, store transposed-source into LDS
#pragma unroll
    for (int p = 0; p < 16; ++p) {
        int kl = p * 4 + (t >> 6);
        int vl = t & 63;
        int v  = v0 + vl;
        float val = (v < V_DIM) ? W[(size_t)(k0 + kl) * V_DIM + v] : 0.0f;
        tile[kl][vl] = f2bf(val);
    }
    __syncthreads();
    // phase 2: coalesced write along k (dword = 2 bf16 per lane)
#pragma unroll
    for (int p = 0; p < 8; ++p) {
        int vl = p * 8 + (t >> 5);
        int k2 = (t & 31) * 2;
        unsigned int pk = (unsigned int)tile[k2][vl] | ((unsigned int)tile[k2 + 1][vl] << 16);
        *(unsigned int*)(wt + (size_t)(v0 + vl) * K_DIM + k0 + k2) = pk;
    }
}

// ---------------- fused GEMM (128x128 tile) + per-row online softmax partials ----------------
__global__ __launch_bounds__(256) void gemm_ce_kernel(
        const unsigned short* __restrict__ xb,   // [N, K] bf16
        const unsigned short* __restrict__ wt,   // [V_PAD, K] bf16
        const int* __restrict__ target,
        float* __restrict__ part_m,              // [N, VB]
        float* __restrict__ part_l,              // [N, VB]
        float* __restrict__ tgt_logit)           // [N]
{
    __shared__ unsigned short As[128 * 32];
    __shared__ unsigned short Bs[128 * 32];
    __shared__ float stats[2][128][2];           // [wave_n][row][m,l]

    const int tid  = threadIdx.x;
    const int lane = tid & 63;
    const int wave = tid >> 6;
    const int wm   = wave & 1;                   // row half
    const int wn   = wave >> 1;                  // col half
    const int n0   = blockIdx.x * 128;
    const int vb   = blockIdx.y;
    const int v0   = vb * 128;

    floatx4 acc[4][4];
#pragma unroll
    for (int i = 0; i < 4; ++i)
#pragma unroll
        for (int j = 0; j < 4; ++j)
            acc[i][j] = (floatx4){0.f, 0.f, 0.f, 0.f};

    const int lrow = lane >> 2;          // 0..15
    const int lk   = (lane & 3) * 8;     // 0,8,16,24
    const unsigned short* gA0 = xb + (size_t)(n0 + wave * 16 + lrow) * K_DIM + lk;
    const unsigned short* gA1 = gA0 + (size_t)64 * K_DIM;
    const unsigned short* gB0 = wt + (size_t)(v0 + wave * 16 + lrow) * K_DIM + lk;
    const unsigned short* gB1 = gB0 + (size_t)64 * K_DIM;
    unsigned short* sA0 = As + wave * 512;
    unsigned short* sA1 = As + 2048 + wave * 512;
    unsigned short* sB0 = Bs + wave * 512;
    unsigned short* sB1 = Bs + 2048 + wave * 512;

    const int am = (wm * 64 + (lane & 15)) * 32 + ((lane >> 4) * 8);
    const int bn = (wn * 64 + (lane & 15)) * 32 + ((lane >> 4) * 8);

    for (int kt = 0; kt < K_DIM / 32; ++kt) {
        const int ko = kt * 32;
        async_copy16(gA0 + ko, sA0);
        async_copy16(gA1 + ko, sA1);
        async_copy16(gB0 + ko, sB0);
        async_copy16(gB1 + ko, sB1);
        __syncthreads();

        bf16x8 af[4], bfv[4];
#pragma unroll
        for (int i = 0; i < 4; ++i) af[i] = *(const bf16x8*)(As + am + i * 512);
#pragma unroll
        for (int j = 0; j < 4; ++j) bfv[j] = *(const bf16x8*)(Bs + bn + j * 512);
#pragma unroll
        for (int i = 0; i < 4; ++i)
#pragma unroll
            for (int j = 0; j < 4; ++j)
                acc[i][j] = __builtin_amdgcn_mfma_f32_16x16x32_bf16(af[i], bfv[j], acc[i][j], 0, 0, 0);
        __syncthreads();
    }

    // ---- epilogue: per-row (m, sum exp) over this block's 128 columns ----
    const int colbase = v0 + wn * 64 + (lane & 15);
    const int rowbase = n0 + wm * 64 + ((lane >> 4) * 4);
#pragma unroll
    for (int i = 0; i < 4; ++i) {
#pragma unroll
        for (int r = 0; r < 4; ++r) {
            const int grow = rowbase + i * 16 + r;
            const int tg   = target[grow];
            float m = -INFINITY;
#pragma unroll
            for (int j = 0; j < 4; ++j) {
                const int col = colbase + j * 16;
                const float val = acc[i][j][r];
                if (col < V_DIM) {
                    if (col == tg) tgt_logit[grow] = val;
                    m = fmaxf(m, val);
                }
            }
            float l = 0.f;
#pragma unroll
            for (int j = 0; j < 4; ++j) {
                const int col = colbase + j * 16;
                if (col < V_DIM) l += __expf(acc[i][j][r] - m);
            }
            // butterfly across the 16 lanes holding this row's 16 columns per tile
#pragma unroll
            for (int off = 1; off < 16; off <<= 1) {
                float om = __shfl_xor(m, off, 64);
                float ol = __shfl_xor(l, off, 64);
                float nm = fmaxf(m, om);
                l = l * __expf(m - nm) + ol * __expf(om - nm);
                m = nm;
            }
            if ((lane & 15) == 0) {
                const int brow = wm * 64 + i * 16 + ((lane >> 4) * 4) + r;
                stats[wn][brow][0] = m;
                stats[wn][brow][1] = l;
            }
        }
    }
    __syncthreads();
    if (tid < 128) {
        const float m0 = stats[0][tid][0], l0 = stats[0][tid][1];
        const float m1 = stats[1][tid][0], l1 = stats[1][tid][1];
        const float M = fmaxf(m0, m1);
        const float L = l0 * __expf(m0 - M) + l1 * __expf(m1 - M);
        const size_t idx = (size_t)(n0 + tid) * VB + vb;
        part_m[idx] = M;
        part_l[idx] = L;
    }
}

// ---------------- merge split-V partials -> per-row loss ----------------
__global__ void reduce_lse_kernel(const float* __restrict__ part_m, const float* __restrict__ part_l,
                                  const float* __restrict__ tgt_logit, const int* __restrict__ target,
                                  float* __restrict__ row_loss) {
    const int row  = blockIdx.x * 4 + (threadIdx.x >> 6);
    const int lane = threadIdx.x & 63;
    const float* pm = part_m + (size_t)row * VB;
    const float* pl = part_l + (size_t)row * VB;
    float M = -INFINITY, L = 0.f;
    for (int j = lane; j < VB; j += 64) {
        const float m = pm[j], l = pl[j];
        const float nm = fmaxf(M, m);
        L = L * __expf(M - nm) + l * __expf(m - nm);
        M = nm;
    }
#pragma unroll
    for (int off = 1; off < 64; off <<= 1) {
        float om = __shfl_xor(M, off, 64);
        float ol = __shfl_xor(L, off, 64);
        float nm = fmaxf(M, om);
        L = L * __expf(M - nm) + ol * __expf(om - nm);
        M = nm;
    }
    if (lane == 0) {
        const float lse = M + __logf(L);
        const int tg = target[row];
        row_loss[row] = (tg == IGNORE_IDX) ? 0.f : (lse - tgt_logit[row]);
    }
}

// ---------------- final mean ----------------
__global__ void final_reduce_kernel(const float* __restrict__ row_loss, const int* __restrict__ target,
                                    float* __restrict__ out) {
    __shared__ float ssum[256];
    __shared__ int   scnt[256];
    const int tid = threadIdx.x;
    float s = 0.f; int c = 0;
    for (int n = tid; n < N_ROWS; n += 256) {
        s += row_loss[n];
        c += (target[n] != IGNORE_IDX) ? 1 : 0;
    }
    ssum[tid] = s; scnt[tid] = c;
    __syncthreads();
    for (int off = 128; off > 0; off >>= 1) {
        if (tid < off) { ssum[tid] += ssum[tid + off]; scnt[tid] += scnt[tid + off]; }
        __syncthreads();
    }
    if (tid == 0) out[0] = ssum[0] / fmaxf((float)scnt[0], 1.0f);
}

// ws-too-small sentinel so the failure mode is distinguishable
__global__ void sentinel_kernel(float* __restrict__ out) { out[0] = -12345.0f; }

extern "C" void kernel_launch(void* const* d_in, const int* in_sizes, int n_in,
                              void* d_out, int out_size, void* d_ws, size_t ws_size,
                              hipStream_t stream) {
    const float* x      = (const float*)d_in[0];
    const float* W      = (const float*)d_in[1];
    const int*   target = (const int*)d_in[2];
    float* out = (float*)d_out;

    // workspace layout (all 256B-aligned)
    const size_t XB_BYTES = (size_t)N_ROWS * K_DIM * 2;          // 16,777,216
    const size_t WT_BYTES = (size_t)V_PAD * K_DIM * 2;           // 206,045,184
    const size_t PM_BYTES = (size_t)N_ROWS * VB * 4;             // 6,438,912
    const size_t PL_BYTES = PM_BYTES;
    const size_t TG_BYTES = (size_t)N_ROWS * 4;
    const size_t RL_BYTES = (size_t)N_ROWS * 4;
    const size_t REQUIRED = XB_BYTES + WT_BYTES + PM_BYTES + PL_BYTES + TG_BYTES + RL_BYTES;

    if (ws_size < REQUIRED) {
        sentinel_kernel<<<1, 1, 0, stream>>>(out);
        return;
    }

    char* ws = (char*)d_ws;
    unsigned short* xb     = (unsigned short*)(ws);
    unsigned short* wt     = (unsigned short*)(ws + XB_BYTES);
    float* part_m          = (float*)(ws + XB_BYTES + WT_BYTES);
    float* part_l          = (float*)(ws + XB_BYTES + WT_BYTES + PM_BYTES);
    float* tgt_logit       = (float*)(ws + XB_BYTES + WT_BYTES + PM_BYTES + PL_BYTES);
    float* row_loss        = (float*)(ws + XB_BYTES + WT_BYTES + PM_BYTES + PL_BYTES + TG_BYTES);

    hipMemsetAsync(tgt_logit, 0, TG_BYTES + RL_BYTES, stream);

    convert_x_kernel<<<(N_ROWS * K_DIM) / (256 * 8), 256, 0, stream>>>(x, xb);
    transpose_w_kernel<<<dim3(V_PAD / 64, K_DIM / 64), 256, 0, stream>>>(W, wt);
    gemm_ce_kernel<<<dim3(N_ROWS / 128, VB), 256, 0, stream>>>(xb, wt, target, part_m, part_l, tgt_logit);
    reduce_lse_kernel<<<N_ROWS / 4, 256, 0, stream>>>(part_m, part_l, tgt_logit, target, row_loss);
    final_reduce_kernel<<<1, 256, 0, stream>>>(row_loss, target, out);
}

// Round 2
// 1656.718 us; speedup vs baseline: 1.3039x; 1.3039x over previous
//
#include <hip/hip_runtime.h>
#include <stdint.h>

// Problem constants
#define N_ROWS 4096
#define K_DIM  2048
#define V_DIM  50257
#define V_PAD  50304              // 393 * 128
#define VB     393                // number of 128-wide v blocks
#define IGNORE_IDX (-100)

#define BM 256
#define BN 128

typedef __attribute__((ext_vector_type(8))) __bf16 bf16x8;
typedef __attribute__((ext_vector_type(4))) float floatx4;

typedef __attribute__((address_space(3))) unsigned int lds_uint;
typedef __attribute__((address_space(1))) const unsigned int gbl_uint;

__device__ __forceinline__ void async_copy16(const unsigned short* g, unsigned short* s) {
    // 16B per lane: global -> LDS direct (wave-uniform LDS base + lane*16)
    __builtin_amdgcn_global_load_lds((gbl_uint*)g, (lds_uint*)s, 16, 0, 0);
}

__device__ __forceinline__ unsigned short f2bf(float f) {
    union { float f; unsigned int u; } v; v.f = f;
    unsigned int r = v.u + 0x7fffu + ((v.u >> 16) & 1u);   // RNE
    return (unsigned short)(r >> 16);
}

__device__ __forceinline__ unsigned int pack2(float lo, float hi) {
    return (unsigned int)f2bf(lo) | ((unsigned int)f2bf(hi) << 16);
}

// ---------------- x fp32 -> bf16 ----------------
__global__ void convert_x_kernel(const float* __restrict__ x, unsigned short* __restrict__ xb) {
    size_t i = ((size_t)blockIdx.x * 256 + threadIdx.x) * 8;
    const float4 a = *(const float4*)(x + i);
    const float4 b = *(const float4*)(x + i + 4);
    uint4 o;
    o.x = pack2(a.x, a.y); o.y = pack2(a.z, a.w);
    o.z = pack2(b.x, b.y); o.w = pack2(b.z, b.w);
    *(uint4*)(xb + i) = o;
}

// ---------------- W [K,V] fp32 -> Wt [V_PAD, K] bf16 (transpose+convert) ----------------
__global__ void transpose_w_kernel(const float* __restrict__ W, unsigned short* __restrict__ wt) {
    __shared__ unsigned short tile[64][66];   // [k][v], pad to 66 to spread banks
    const int t  = threadIdx.x;
    const int v0 = blockIdx.x * 64;
    const int k0 = blockIdx.y * 64;
#pragma unroll
    for (int p = 0; p < 16; ++p) {
        int kl = p * 4 + (t >> 6);
        int vl = t & 63;
        int v  = v0 + vl;
        float val = (v < V_DIM) ? W[(size_t)(k0 + kl) * V_DIM + v] : 0.0f;
        tile[kl][vl] = f2bf(val);
    }
    __syncthreads();
#pragma unroll
    for (int p = 0; p < 8; ++p) {
        int vl = p * 8 + (t >> 5);
        int k2 = (t & 31) * 2;
        unsigned int pk = (unsigned int)tile[k2][vl] | ((unsigned int)tile[k2 + 1][vl] << 16);
        *(unsigned int*)(wt + (size_t)(v0 + vl) * K_DIM + k0 + k2) = pk;
    }
}

// ---------------- fused GEMM (256x128 tile) + per-row online softmax partials ----------------
// LDS k-chunk swizzle: logical chunk c (16B) of row r lives at physical chunk c ^ ((r>>1)&3).
// Compatible with global_load_lds (lane*16 contiguous dest): we permute the GLOBAL source
// chunk per lane instead of the LDS destination.
__global__ __launch_bounds__(256, 2) void gemm_ce_kernel(
        const unsigned short* __restrict__ xb,   // [N, K] bf16
        const unsigned short* __restrict__ wt,   // [V_PAD, K] bf16
        const int* __restrict__ target,
        float* __restrict__ part_m,              // [N, VB]
        float* __restrict__ part_l,              // [N, VB]
        float* __restrict__ tgt_logit)           // [N]
{
    __shared__ unsigned short As[BM * 32];       // 16 KB
    __shared__ unsigned short Bs[BN * 32];       // 8 KB
    __shared__ float stats[2][BM][2];            // 4 KB  [wave_n][row][m,l]

    const int tid  = threadIdx.x;
    const int lane = tid & 63;
    const int wave = tid >> 6;
    const int wm   = wave & 1;                   // row half (128 rows each)
    const int wn   = wave >> 1;                  // col half (64 cols each)
    const int n0   = blockIdx.x * BM;
    const int vb   = blockIdx.y;
    const int v0   = vb * BN;

    floatx4 acc[8][4];
#pragma unroll
    for (int i = 0; i < 8; ++i)
#pragma unroll
        for (int j = 0; j < 4; ++j)
            acc[i][j] = (floatx4){0.f, 0.f, 0.f, 0.f};

    // ---- staging addresses (swizzled global k-chunk) ----
    const int lrow = lane >> 2;                           // 0..15 row within 16-row copy
    const int lk   = (((lane & 3) ^ ((lrow >> 1) & 3))) * 8;  // swizzled k offset (shorts)
    // A: wave covers rows [wave*64, wave*64+64), 4 copies of 16 rows
    const unsigned short* gA = xb + (size_t)(n0 + wave * 64 + lrow) * K_DIM + lk;
    unsigned short* sA = As + (wave * 64) * 32;
    // B: wave covers rows [wave*32, wave*32+32), 2 copies of 16 rows
    const unsigned short* gB = wt + (size_t)(v0 + wave * 32 + lrow) * K_DIM + lk;
    unsigned short* sB = Bs + (wave * 32) * 32;

    // ---- fragment read offsets (swizzled physical chunk) ----
    const int r16  = lane & 15;
    const int cq   = lane >> 4;                           // logical k-chunk 0..3
    const int pq   = cq ^ ((r16 >> 1) & 3);               // physical k-chunk
    const int am   = (wm * 128 + r16) * 32 + pq * 8;      // shorts
    const int bn   = (wn * 64 + r16) * 32 + pq * 8;

    for (int kt = 0; kt < K_DIM / 32; ++kt) {
        const int ko = kt * 32;
#pragma unroll
        for (int q = 0; q < 4; ++q)
            async_copy16(gA + (size_t)(q * 16) * K_DIM + ko, sA + q * 512);
#pragma unroll
        for (int q = 0; q < 2; ++q)
            async_copy16(gB + (size_t)(q * 16) * K_DIM + ko, sB + q * 512);
        __syncthreads();

        bf16x8 af[8], bfv[4];
#pragma unroll
        for (int i = 0; i < 8; ++i) af[i] = *(const bf16x8*)(As + am + i * 512);
#pragma unroll
        for (int j = 0; j < 4; ++j) bfv[j] = *(const bf16x8*)(Bs + bn + j * 512);
#pragma unroll
        for (int i = 0; i < 8; ++i)
#pragma unroll
            for (int j = 0; j < 4; ++j)
                acc[i][j] = __builtin_amdgcn_mfma_f32_16x16x32_bf16(af[i], bfv[j], acc[i][j], 0, 0, 0);
        __syncthreads();
    }

    // ---- epilogue: per-row (m, sum exp) over this block's 128 columns ----
    const int colg = v0 + wn * 64 + r16;
    const int rq   = cq * 4;
#pragma unroll
    for (int i = 0; i < 8; ++i) {
#pragma unroll
        for (int r = 0; r < 4; ++r) {
            const int brow = wm * 128 + i * 16 + rq + r;
            const int grow = n0 + brow;
            const int tg   = target[grow];
            float m = -INFINITY;
#pragma unroll
            for (int j = 0; j < 4; ++j) {
                const int col = colg + j * 16;
                const float val = acc[i][j][r];
                if (col < V_DIM) {
                    m = fmaxf(m, val);
                    if (col == tg) tgt_logit[grow] = val;
                }
            }
            // row max across the 16 lanes holding this row's columns
#pragma unroll
            for (int off = 1; off < 16; off <<= 1)
                m = fmaxf(m, __shfl_xor(m, off, 64));
            float l = 0.f;
#pragma unroll
            for (int j = 0; j < 4; ++j) {
                const int col = colg + j * 16;
                if (col < V_DIM) l += __expf(acc[i][j][r] - m);
            }
#pragma unroll
            for (int off = 1; off < 16; off <<= 1)
                l += __shfl_xor(l, off, 64);
            if (r16 == 0) {
                stats[wn][brow][0] = m;
                stats[wn][brow][1] = l;
            }
        }
    }
    __syncthreads();
    if (tid < BM) {
        const float m0 = stats[0][tid][0], l0 = stats[0][tid][1];
        const float m1 = stats[1][tid][0], l1 = stats[1][tid][1];
        const float M = fmaxf(m0, m1);
        const float L = l0 * __expf(m0 - M) + l1 * __expf(m1 - M);
        const size_t idx = (size_t)(n0 + tid) * VB + vb;
        part_m[idx] = M;
        part_l[idx] = L;
    }
}

// ---------------- merge split-V partials -> per-row loss ----------------
__global__ void reduce_lse_kernel(const float* __restrict__ part_m, const float* __restrict__ part_l,
                                  const float* __restrict__ tgt_logit, const int* __restrict__ target,
                                  float* __restrict__ row_loss) {
    const int row  = blockIdx.x * 4 + (threadIdx.x >> 6);
    const int lane = threadIdx.x & 63;
    const float* pm = part_m + (size_t)row * VB;
    const float* pl = part_l + (size_t)row * VB;
    float M = -INFINITY, L = 0.f;
    for (int j = lane; j < VB; j += 64) {
        const float m = pm[j], l = pl[j];
        const float nm = fmaxf(M, m);
        L = L * __expf(M - nm) + l * __expf(m - nm);
        M = nm;
    }
#pragma unroll
    for (int off = 1; off < 64; off <<= 1) {
        float om = __shfl_xor(M, off, 64);
        float ol = __shfl_xor(L, off, 64);
        float nm = fmaxf(M, om);
        L = L * __expf(M - nm) + ol * __expf(om - nm);
        M = nm;
    }
    if (lane == 0) {
        const float lse = M + __logf(L);
        const int tg = target[row];
        row_loss[row] = (tg == IGNORE_IDX) ? 0.f : (lse - tgt_logit[row]);
    }
}

// ---------------- final mean ----------------
__global__ void final_reduce_kernel(const float* __restrict__ row_loss, const int* __restrict__ target,
                                    float* __restrict__ out) {
    __shared__ float ssum[256];
    __shared__ int   scnt[256];
    const int tid = threadIdx.x;
    float s = 0.f; int c = 0;
    for (int n = tid; n < N_ROWS; n += 256) {
        s += row_loss[n];
        c += (target[n] != IGNORE_IDX) ? 1 : 0;
    }
    ssum[tid] = s; scnt[tid] = c;
    __syncthreads();
    for (int off = 128; off > 0; off >>= 1) {
        if (tid < off) { ssum[tid] += ssum[tid + off]; scnt[tid] += scnt[tid + off]; }
        __syncthreads();
    }
    if (tid == 0) out[0] = ssum[0] / fmaxf((float)scnt[0], 1.0f);
}

// ws-too-small sentinel so the failure mode is distinguishable
__global__ void sentinel_kernel(float* __restrict__ out) { out[0] = -12345.0f; }

extern "C" void kernel_launch(void* const* d_in, const int* in_sizes, int n_in,
                              void* d_out, int out_size, void* d_ws, size_t ws_size,
                              hipStream_t stream) {
    const float* x      = (const float*)d_in[0];
    const float* W      = (const float*)d_in[1];
    const int*   target = (const int*)d_in[2];
    float* out = (float*)d_out;

    const size_t XB_BYTES = (size_t)N_ROWS * K_DIM * 2;          // 16,777,216
    const size_t WT_BYTES = (size_t)V_PAD * K_DIM * 2;           // 206,045,184
    const size_t PM_BYTES = (size_t)N_ROWS * VB * 4;             // 6,438,912
    const size_t PL_BYTES = PM_BYTES;
    const size_t TG_BYTES = (size_t)N_ROWS * 4;
    const size_t RL_BYTES = (size_t)N_ROWS * 4;
    const size_t REQUIRED = XB_BYTES + WT_BYTES + PM_BYTES + PL_BYTES + TG_BYTES + RL_BYTES;

    if (ws_size < REQUIRED) {
        sentinel_kernel<<<1, 1, 0, stream>>>(out);
        return;
    }

    char* ws = (char*)d_ws;
    unsigned short* xb     = (unsigned short*)(ws);
    unsigned short* wt     = (unsigned short*)(ws + XB_BYTES);
    float* part_m          = (float*)(ws + XB_BYTES + WT_BYTES);
    float* part_l          = (float*)(ws + XB_BYTES + WT_BYTES + PM_BYTES);
    float* tgt_logit       = (float*)(ws + XB_BYTES + WT_BYTES + PM_BYTES + PL_BYTES);
    float* row_loss        = (float*)(ws + XB_BYTES + WT_BYTES + PM_BYTES + PL_BYTES + TG_BYTES);

    convert_x_kernel<<<(N_ROWS * K_DIM) / (256 * 8), 256, 0, stream>>>(x, xb);
    transpose_w_kernel<<<dim3(V_PAD / 64, K_DIM / 64), 256, 0, stream>>>(W, wt);
    gemm_ce_kernel<<<dim3(N_ROWS / BM, VB), 256, 0, stream>>>(xb, wt, target, part_m, part_l, tgt_logit);
    reduce_lse_kernel<<<N_ROWS / 4, 256, 0, stream>>>(part_m, part_l, tgt_logit, target, row_loss);
    final_reduce_kernel<<<1, 256, 0, stream>>>(row_loss, target, out);
}

// Round 3
// 1269.271 us; speedup vs baseline: 1.7019x; 1.3053x over previous
//
#include <hip/hip_runtime.h>
#include <stdint.h>

// Problem constants
#define N_ROWS 4096
#define K_DIM  2048
#define V_DIM  50257
#define V_PAD  50304              // 393 * 128
#define VB     393                // number of 128-wide v blocks
#define IGNORE_IDX (-100)

#define BM 256
#define BN 128
#define BK 64
#define WSCL     16.0f            // W scaled by 16 before fp8 (dodge subnormals)
#define WSCL_INV 0.0625f

typedef __attribute__((ext_vector_type(4))) float floatx4;

typedef __attribute__((address_space(3))) unsigned int lds_uint;
typedef __attribute__((address_space(1))) const unsigned int gbl_uint;

__device__ __forceinline__ void async_copy16(const unsigned char* g, unsigned char* s) {
    // 16B per lane: global -> LDS direct (wave-uniform LDS base + lane*16)
    __builtin_amdgcn_global_load_lds((gbl_uint*)g, (lds_uint*)s, 16, 0, 0);
}

// float -> OCP e4m3fn with RNE, manual bit path (no builtin/header dependency).
// Inputs here never exceed ~6 in magnitude (well under 448 sat).
__device__ __forceinline__ unsigned int f2fp8(float f) {
    union { float f; unsigned int u; } v; v.f = f;
    const unsigned int s = (v.u >> 24) & 0x80u;
    const unsigned int a = v.u & 0x7FFFFFFFu;
    if (a >= 0x43E00000u) return s | 0x7Eu;          // >= 448 -> saturate to 448
    if (a < 0x3C800000u) {                           // < 2^-6 -> e4m3 subnormal
        union { float f; unsigned int u; } w; w.u = a;
        const int n = (int)rintf(w.f * 512.0f);      // quantize to 2^-9 steps, RNE
        return s | (unsigned int)n;                  // n in 0..8 (8 == 2^-6 normal)
    }
    const unsigned int r  = a + 0x7FFFFu + ((a >> 20) & 1u);  // RNE into 3-bit mantissa
    const unsigned int e8 = (r >> 23) - 120u;        // rebias 127 -> 7
    const unsigned int m3 = (r >> 20) & 7u;
    return s | (e8 << 3) | m3;
}

// ---------------- x fp32 -> fp8 [N, K] ----------------
__global__ void convert_x_kernel(const float* __restrict__ x, unsigned char* __restrict__ xb) {
    const size_t i = ((size_t)blockIdx.x * 256 + threadIdx.x) * 16;
    uint4 o;
    unsigned int w[4];
#pragma unroll
    for (int g = 0; g < 4; ++g) {
        const float4 f = *(const float4*)(x + i + g * 4);
        w[g] = f2fp8(f.x) | (f2fp8(f.y) << 8) | (f2fp8(f.z) << 16) | (f2fp8(f.w) << 24);
    }
    o.x = w[0]; o.y = w[1]; o.z = w[2]; o.w = w[3];
    *(uint4*)(xb + i) = o;
}

// ---------------- W [K,V] fp32 -> Wt [V_PAD, K] fp8 (transpose+convert, x16) ----------------
// Block: 64 k x 128 v. Phase 1: coalesced reads along v, pack 4 fp8 into u32 tile.
// Phase 2: each lane gathers a 16-byte k-run for one v row, stores dwordx4.
__global__ void transpose_w_kernel(const float* __restrict__ W, unsigned char* __restrict__ wt) {
    __shared__ unsigned int t32[64][33];             // [k][v/4], pitch 33 breaks conflicts
    const int tid = threadIdx.x;
    const int v0  = blockIdx.x * 128;
    const int k0  = blockIdx.y * 64;
    const int vl  = tid & 31;                        // v/4 within tile
    const int kh  = tid >> 5;                        // 8 k rows per pass
#pragma unroll
    for (int p = 0; p < 8; ++p) {
        const int kl = p * 8 + kh;
        const float* row = W + (size_t)(k0 + kl) * V_DIM;
        unsigned int u = 0;
#pragma unroll
        for (int e = 0; e < 4; ++e) {
            const int v = v0 + vl * 4 + e;
            const float f = (v < V_DIM) ? row[v] : 0.0f;
            u |= f2fp8(f * WSCL) << (8 * e);
        }
        t32[kl][vl] = u;
    }
    __syncthreads();
    const int kc = tid & 3;                          // 16-byte k chunk
#pragma unroll
    for (int p = 0; p < 2; ++p) {
        const int vr  = p * 64 + (tid >> 2);         // v row within tile
        const int v4  = vr >> 2;
        const int vsh = (vr & 3) * 8;
        unsigned int w[4];
#pragma unroll
        for (int g = 0; g < 4; ++g) {
            unsigned int r = 0;
#pragma unroll
            for (int b = 0; b < 4; ++b) {
                const int k = kc * 16 + g * 4 + b;
                r |= ((t32[k][v4] >> vsh) & 0xFFu) << (8 * b);
            }
            w[g] = r;
        }
        uint4 o; o.x = w[0]; o.y = w[1]; o.z = w[2]; o.w = w[3];
        *(uint4*)(wt + (size_t)(v0 + vr) * K_DIM + k0 + kc * 16) = o;
    }
}

// ---------------- fused fp8 GEMM (256x128x64 tile) + per-row softmax partials ----------------
// LDS k-chunk XOR swizzle (16B chunks): logical chunk c of row r lives at c ^ ((r&15)>>1 & 3).
// Staging permutes the GLOBAL source chunk per lane (global_load_lds dest is lane*16 fixed).
__global__ __launch_bounds__(256, 2) void gemm_ce_kernel(
        const unsigned char* __restrict__ xb,    // [N, K] fp8
        const unsigned char* __restrict__ wt,    // [V_PAD, K] fp8 (x16 scaled)
        const int* __restrict__ target,
        float* __restrict__ part_m,              // [N, VB]
        float* __restrict__ part_l,              // [N, VB]
        float* __restrict__ tgt_logit)           // [N]
{
    __shared__ unsigned char As[BM * BK];        // 16 KB
    __shared__ unsigned char Bs[BN * BK];        // 8 KB
    __shared__ float stats[2][BM][2];            // 4 KB

    const int tid  = threadIdx.x;
    const int lane = tid & 63;
    const int wave = tid >> 6;
    const int wm   = wave & 1;                   // row half (128 rows each)
    const int wn   = wave >> 1;                  // col half (64 cols each)
    const int n0   = blockIdx.x * BM;
    const int vb   = blockIdx.y;
    const int v0   = vb * BN;

    floatx4 acc[8][4];
#pragma unroll
    for (int i = 0; i < 8; ++i)
#pragma unroll
        for (int j = 0; j < 4; ++j)
            acc[i][j] = (floatx4){0.f, 0.f, 0.f, 0.f};

    // ---- staging addresses (swizzled global k-chunk), 16 fp8 per 16B chunk ----
    const int lrow = lane >> 2;                              // 0..15 row in 16-row copy
    const int lk   = ((lane & 3) ^ ((lrow >> 1) & 3)) * 16;  // swizzled k byte offset
    const unsigned char* gA = xb + (size_t)(n0 + wave * 64 + lrow) * K_DIM + lk;
    const unsigned char* gB = wt + (size_t)(v0 + wave * 32 + lrow) * K_DIM + lk;
    unsigned char* sA = As + wave * 4096;        // 64 rows x 64B per wave
    unsigned char* sB = Bs + wave * 2048;        // 32 rows x 64B per wave

    // ---- fragment read offsets ----
    const int r16   = lane & 15;
    const int cq    = lane >> 4;                 // k quarter 0..3 (8 fp8 each per s)
    const int sw    = (r16 >> 1) & 3;
    const int abase = (wm * 128 + r16) * BK + (cq & 1) * 8;
    const int bbase = (wn * 64  + r16) * BK + (cq & 1) * 8;

    for (int kt = 0; kt < K_DIM / BK; ++kt) {
        const int ko = kt * BK;
#pragma unroll
        for (int q = 0; q < 4; ++q)
            async_copy16(gA + (size_t)(q * 16) * K_DIM + ko, sA + q * 1024);
#pragma unroll
        for (int q = 0; q < 2; ++q)
            async_copy16(gB + (size_t)(q * 16) * K_DIM + ko, sB + q * 1024);
        __syncthreads();

#pragma unroll
        for (int s = 0; s < 2; ++s) {
            const int ph = ((2 * s + (cq >> 1)) ^ sw) * 16;  // physical 16B chunk
            long long a8[8], b8[4];
#pragma unroll
            for (int i = 0; i < 8; ++i) a8[i] = *(const long long*)(As + abase + i * 1024 + ph);
#pragma unroll
            for (int j = 0; j < 4; ++j) b8[j] = *(const long long*)(Bs + bbase + j * 1024 + ph);
#pragma unroll
            for (int i = 0; i < 8; ++i)
#pragma unroll
                for (int j = 0; j < 4; ++j)
                    acc[i][j] = __builtin_amdgcn_mfma_f32_16x16x32_fp8_fp8(a8[i], b8[j], acc[i][j], 0, 0, 0);
        }
        __syncthreads();
    }

    // ---- epilogue: per-row (m, sum exp) over this block's 128 columns ----
    const int colg = v0 + wn * 64 + r16;
    const int rq   = cq * 4;
#pragma unroll
    for (int i = 0; i < 8; ++i) {
#pragma unroll
        for (int r = 0; r < 4; ++r) {
            const int brow = wm * 128 + i * 16 + rq + r;
            const int grow = n0 + brow;
            const int tg   = target[grow];
            float m = -INFINITY;
#pragma unroll
            for (int j = 0; j < 4; ++j) {
                const int col = colg + j * 16;
                const float val = acc[i][j][r] * WSCL_INV;
                if (col < V_DIM) {
                    m = fmaxf(m, val);
                    if (col == tg) tgt_logit[grow] = val;
                }
            }
#pragma unroll
            for (int off = 1; off < 16; off <<= 1)
                m = fmaxf(m, __shfl_xor(m, off, 64));
            float l = 0.f;
#pragma unroll
            for (int j = 0; j < 4; ++j) {
                const int col = colg + j * 16;
                if (col < V_DIM) l += __expf(acc[i][j][r] * WSCL_INV - m);
            }
#pragma unroll
            for (int off = 1; off < 16; off <<= 1)
                l += __shfl_xor(l, off, 64);
            if (r16 == 0) {
                stats[wn][brow][0] = m;
                stats[wn][brow][1] = l;
            }
        }
    }
    __syncthreads();
    if (tid < BM) {
        const float m0 = stats[0][tid][0], l0 = stats[0][tid][1];
        const float m1 = stats[1][tid][0], l1 = stats[1][tid][1];
        const float M = fmaxf(m0, m1);
        const float L = l0 * __expf(m0 - M) + l1 * __expf(m1 - M);
        const size_t idx = (size_t)(n0 + tid) * VB + vb;
        part_m[idx] = M;
        part_l[idx] = L;
    }
}

// ---------------- merge split-V partials -> per-row loss ----------------
__global__ void reduce_lse_kernel(const float* __restrict__ part_m, const float* __restrict__ part_l,
                                  const float* __restrict__ tgt_logit, const int* __restrict__ target,
                                  float* __restrict__ row_loss) {
    const int row  = blockIdx.x * 4 + (threadIdx.x >> 6);
    const int lane = threadIdx.x & 63;
    const float* pm = part_m + (size_t)row * VB;
    const float* pl = part_l + (size_t)row * VB;
    float M = -INFINITY, L = 0.f;
    for (int j = lane; j < VB; j += 64) {
        const float m = pm[j], l = pl[j];
        const float nm = fmaxf(M, m);
        L = L * __expf(M - nm) + l * __expf(m - nm);
        M = nm;
    }
#pragma unroll
    for (int off = 1; off < 64; off <<= 1) {
        float om = __shfl_xor(M, off, 64);
        float ol = __shfl_xor(L, off, 64);
        float nm = fmaxf(M, om);
        L = L * __expf(M - nm) + ol * __expf(om - nm);
        M = nm;
    }
    if (lane == 0) {
        const float lse = M + __logf(L);
        const int tg = target[row];
        row_loss[row] = (tg == IGNORE_IDX) ? 0.f : (lse - tgt_logit[row]);
    }
}

// ---------------- final mean ----------------
__global__ void final_reduce_kernel(const float* __restrict__ row_loss, const int* __restrict__ target,
                                    float* __restrict__ out) {
    __shared__ float ssum[256];
    __shared__ int   scnt[256];
    const int tid = threadIdx.x;
    float s = 0.f; int c = 0;
    for (int n = tid; n < N_ROWS; n += 256) {
        s += row_loss[n];
        c += (target[n] != IGNORE_IDX) ? 1 : 0;
    }
    ssum[tid] = s; scnt[tid] = c;
    __syncthreads();
    for (int off = 128; off > 0; off >>= 1) {
        if (tid < off) { ssum[tid] += ssum[tid + off]; scnt[tid] += scnt[tid + off]; }
        __syncthreads();
    }
    if (tid == 0) out[0] = ssum[0] / fmaxf((float)scnt[0], 1.0f);
}

// ws-too-small sentinel so the failure mode is distinguishable
__global__ void sentinel_kernel(float* __restrict__ out) { out[0] = -12345.0f; }

extern "C" void kernel_launch(void* const* d_in, const int* in_sizes, int n_in,
                              void* d_out, int out_size, void* d_ws, size_t ws_size,
                              hipStream_t stream) {
    const float* x      = (const float*)d_in[0];
    const float* W      = (const float*)d_in[1];
    const int*   target = (const int*)d_in[2];
    float* out = (float*)d_out;

    const size_t XB_BYTES = (size_t)N_ROWS * K_DIM;              // 8,388,608
    const size_t WT_BYTES = (size_t)V_PAD * K_DIM;               // 103,022,592
    const size_t PM_BYTES = (size_t)N_ROWS * VB * 4;             // 6,438,912
    const size_t PL_BYTES = PM_BYTES;
    const size_t TG_BYTES = (size_t)N_ROWS * 4;
    const size_t RL_BYTES = (size_t)N_ROWS * 4;
    const size_t REQUIRED = XB_BYTES + WT_BYTES + PM_BYTES + PL_BYTES + TG_BYTES + RL_BYTES;

    if (ws_size < REQUIRED) {
        sentinel_kernel<<<1, 1, 0, stream>>>(out);
        return;
    }

    char* ws = (char*)d_ws;
    unsigned char* xb = (unsigned char*)(ws);
    unsigned char* wt = (unsigned char*)(ws + XB_BYTES);
    float* part_m     = (float*)(ws + XB_BYTES + WT_BYTES);
    float* part_l     = (float*)(ws + XB_BYTES + WT_BYTES + PM_BYTES);
    float* tgt_logit  = (float*)(ws + XB_BYTES + WT_BYTES + PM_BYTES + PL_BYTES);
    float* row_loss   = (float*)(ws + XB_BYTES + WT_BYTES + PM_BYTES + PL_BYTES + TG_BYTES);

    convert_x_kernel<<<(N_ROWS * K_DIM) / (256 * 16), 256, 0, stream>>>(x, xb);
    transpose_w_kernel<<<dim3(V_PAD / 128, K_DIM / 64), 256, 0, stream>>>(W, wt);
    gemm_ce_kernel<<<dim3(N_ROWS / BM, VB), 256, 0, stream>>>(xb, wt, target, part_m, part_l, tgt_logit);
    reduce_lse_kernel<<<N_ROWS / 4, 256, 0, stream>>>(part_m, part_l, tgt_logit, target, row_loss);
    final_reduce_kernel<<<1, 256, 0, stream>>>(row_loss, target, out);
}